// Round 10
// baseline (478.050 us; speedup 1.0000x reference)
//
#include <hip/hip_runtime.h>
#include <hip/hip_bf16.h>
#include <cstdint>
#include <cstddef>

// ---------------------------------------------------------------------------
// EnhancedBVHRouter forward, MI355X/gfx950. Round 10.
// gemm1k: round-7 exact (best proven: 285us, 4 blocks/CU, A-panel XCD swizzle).
// Tail: same kernels, higher block residency — gemm2 at BM=64 (1024 blocks),
// level GEMMs at BN=64/ntiles=2 (1024 blocks, 4-5 blocks/CU).
// All GEMMs bf16x3 (hi/lo split, 3 MFMA), f32-class precision.
// ---------------------------------------------------------------------------

typedef short  s8v  __attribute__((ext_vector_type(8)));
typedef float  f4v  __attribute__((ext_vector_type(4)));
typedef float  f16v __attribute__((ext_vector_type(16)));
typedef unsigned int u32;

#define B_ROWS 32768

__device__ inline short f2bf(float x) {
    __hip_bfloat16 h = __float2bfloat16(x);
    return __builtin_bit_cast(short, h);
}
__device__ inline float bf2f(short s) {
    return __bfloat162float(__builtin_bit_cast(__hip_bfloat16, s));
}
__device__ inline float gelu_f(float x) {
    return 0.5f * x * (1.0f + erff(x * 0.70710678118654752440f));
}
__device__ inline void gload_lds16(const short* g, short* l) {
    __builtin_amdgcn_global_load_lds(
        (const __attribute__((address_space(1))) u32*)g,
        (__attribute__((address_space(3))) u32*)l, 16, 0, 0);
}

// ---------------------------------------------------------------------------
// W1 -> LDS-image (round-3 proven).
// ---------------------------------------------------------------------------
__global__ void split_w1_img(const float* __restrict__ W, short* __restrict__ img)
{
    const int idx = blockIdx.x * 256 + threadIdx.x;     // 64*512*8 total
    const int p = idx & 7;
    const int n = (idx >> 3) & 511;
    const int t = idx >> 12;
    const int cs = p ^ (n & 7);
    const int plane = cs >> 2, kc = cs & 3;
    const int kbase = t * 32 + kc * 8;
    s8v v8;
    #pragma unroll
    for (int e = 0; e < 8; ++e) {
        const float v = W[(size_t)(kbase + e) * 512 + n];
        const short h = f2bf(v);
        v8[e] = plane ? f2bf(v - bf2f(h)) : h;
    }
    *(s8v*)&img[(size_t)((t * 512 + n) * 64 + p * 8)] = v8;
}

// ---------------------------------------------------------------------------
// GEMM1 (round-7 exact: proven 285us).
// ---------------------------------------------------------------------------
__launch_bounds__(256, 4)
__global__ void gemm1k(const float* __restrict__ X,
                       const short* __restrict__ Bimg,
                       const float* __restrict__ bias,
                       float* __restrict__ out)
{
    __shared__ short smem[128 * 64 * 2];
    short* Ab = smem;
    short* Bb = smem + 128 * 64;

    const int tid = threadIdx.x;
    const int l = tid & 63, wid = tid >> 6;
    const int wr = wid >> 1, wc = wid & 1;

    // A-panel-sharing swizzle (round-7 proven: FETCH 538->192MB)
    const int d = blockIdx.x;                 // 1024 blocks
    const int xcd = d & 7, s = d >> 3;
    const int m0 = (xcd * 32 + (s >> 2)) * 128;
    const int n0 = (s & 3) * 128;

    const int ar = tid & 127, ah = tid >> 7;
    const float* xP = X + (size_t)(m0 + ar) * 2048 + ah * 16;
    short* awr = Ab + ar * 64;
    const int pw0 = ((ah * 2    ) ^ (ar & 7)) * 8;
    const int pw1 = ((ah * 2 + 1) ^ (ar & 7)) * 8;
    const int pw2 = ((ah * 2 + 4) ^ (ar & 7)) * 8;
    const int pw3 = ((ah * 2 + 5) ^ (ar & 7)) * 8;

    const short* bP = Bimg + (size_t)n0 * 64 + (size_t)(wid * 4) * 512 + (size_t)l * 8;
    short* bD = Bb + wid * 4 * 512;

    f16v acc[2][2];
    #pragma unroll
    for (int m = 0; m < 2; ++m)
        #pragma unroll
        for (int n = 0; n < 2; ++n) acc[m][n] = (f16v)0.0f;

    f4v cur0, cur1, cur2, cur3;
    cur0 = *(const f4v*)(xP + 0);
    cur1 = *(const f4v*)(xP + 4);
    cur2 = *(const f4v*)(xP + 8);
    cur3 = *(const f4v*)(xP + 12);

    for (int t = 0; t < 64; ++t) {
        s8v hi0, hi1, lo0, lo1;
        #pragma unroll
        for (int e = 0; e < 4; ++e) {
            float v;
            short h;
            v = cur0[e]; h = f2bf(v); hi0[e]     = h; lo0[e]     = f2bf(v - bf2f(h));
            v = cur1[e]; h = f2bf(v); hi0[e + 4] = h; lo0[e + 4] = f2bf(v - bf2f(h));
            v = cur2[e]; h = f2bf(v); hi1[e]     = h; lo1[e]     = f2bf(v - bf2f(h));
            v = cur3[e]; h = f2bf(v); hi1[e + 4] = h; lo1[e + 4] = f2bf(v - bf2f(h));
        }
        __syncthreads();
        *(s8v*)&awr[pw0] = hi0;
        *(s8v*)&awr[pw1] = hi1;
        *(s8v*)&awr[pw2] = lo0;
        *(s8v*)&awr[pw3] = lo1;
        {
            const short* bt = bP + (size_t)t * 32768;
            gload_lds16(bt,          bD);
            gload_lds16(bt +  512,   bD + 512);
            gload_lds16(bt + 1024,   bD + 1024);
            gload_lds16(bt + 1536,   bD + 1536);
        }
        if (t < 63) {
            const float* p = xP + (t + 1) * 32;
            cur0 = *(const f4v*)(p + 0);
            cur1 = *(const f4v*)(p + 4);
            cur2 = *(const f4v*)(p + 8);
            cur3 = *(const f4v*)(p + 12);
        }
        __syncthreads();

        #pragma unroll
        for (int ks = 0; ks < 2; ++ks) {
            const int ph0 = ks * 2 + (l >> 5);
            s8v ahf[2], alf[2], bhf[2], blf[2];
            #pragma unroll
            for (int m = 0; m < 2; ++m) {
                const int row = wr * 64 + m * 32 + (l & 31);
                const int ph = ph0 ^ (row & 7);
                ahf[m] = *(const s8v*)&Ab[row * 64 + ph * 8];
                alf[m] = *(const s8v*)&Ab[row * 64 + (ph ^ 4) * 8];
            }
            #pragma unroll
            for (int n = 0; n < 2; ++n) {
                const int col = wc * 64 + n * 32 + (l & 31);
                const int ph = ph0 ^ (col & 7);
                bhf[n] = *(const s8v*)&Bb[col * 64 + ph * 8];
                blf[n] = *(const s8v*)&Bb[col * 64 + (ph ^ 4) * 8];
            }
            #pragma unroll
            for (int m = 0; m < 2; ++m)
                #pragma unroll
                for (int n = 0; n < 2; ++n) {
                    acc[m][n] = __builtin_amdgcn_mfma_f32_32x32x16_bf16(ahf[m], bhf[n], acc[m][n], 0, 0, 0);
                    acc[m][n] = __builtin_amdgcn_mfma_f32_32x32x16_bf16(ahf[m], blf[n], acc[m][n], 0, 0, 0);
                    acc[m][n] = __builtin_amdgcn_mfma_f32_32x32x16_bf16(alf[m], bhf[n], acc[m][n], 0, 0, 0);
                }
        }
    }

    #pragma unroll
    for (int m = 0; m < 2; ++m) {
        #pragma unroll
        for (int n = 0; n < 2; ++n) {
            const int gcol = n0 + wc * 64 + n * 32 + (l & 31);
            const float bv = bias[gcol];
            #pragma unroll
            for (int r = 0; r < 16; ++r) {
                const int grow = m0 + wr * 64 + m * 32
                               + (r & 3) + 8 * (r >> 2) + 4 * (l >> 5);
                out[(size_t)grow * 512 + gcol] = gelu_f(acc[m][n][r] + bv);
            }
        }
    }
}

// ---------------------------------------------------------------------------
// Weight split: W (K x N f32) -> [2][N][Kpad] bf16 planes.
// ---------------------------------------------------------------------------
struct SplitDesc { const float* W; short* dst; int K, N, Kpad, blk0; };
struct SplitPack { SplitDesc d[9]; };

__global__ void split_all(SplitPack p) {
    const int bid = blockIdx.x;
    int i = 0;
    #pragma unroll
    for (int j = 1; j < 9; ++j) if (bid >= p.d[j].blk0) i = j;
    const SplitDesc& D = p.d[i];
    const int idx = (bid - D.blk0) * 256 + threadIdx.x;
    const int total = D.N * D.Kpad;
    if (idx >= total) return;
    const int n = idx / D.Kpad, k = idx - n * D.Kpad;
    const float v = (k < D.K) ? D.W[(size_t)k * D.N + n] : 0.0f;
    const short hs = f2bf(v);
    D.dst[idx] = hs;
    D.dst[total + idx] = f2bf(v - bf2f(hs));
}

// ---------------------------------------------------------------------------
// gemm32 (round-7): bf16x3, dbuf LDS, 2-phase prefetch, output stride.
// EPI: 0 = +bias,gelu ; 1 = +bias ; 2 = softmax64+argmax (ostr unused).
// ---------------------------------------------------------------------------
template<int BM, int BN, int EPI>
__launch_bounds__(256, 2)
__global__ void gemm32(const float* __restrict__ A, int lda,
                       const short* __restrict__ Bsp, int ldb, int NK,
                       const float* __restrict__ bias, int K, int N, int ntiles,
                       int ostr, float* __restrict__ out, float* __restrict__ out2)
{
    constexpr int MF  = BM / 64;
    constexpr int NFw = BN / 64;
    constexpr int BUF = (BM + BN) * 64;
    constexpr int FPT = BM / 8;
    constexpr int TPR = 32 / FPT;
    constexpr int nBI = BN / 32;
    __shared__ short smem[2 * BUF];

    const int tid = threadIdx.x;
    const int l   = tid & 63, wid = tid >> 6;
    const int wr  = wid >> 1, wc = wid & 1;
    const int bid = blockIdx.x;
    const int ntb = bid % ntiles, mtb = bid / ntiles;
    const int m0  = mtb * BM, n0 = ntb * BN;

    const int ar = tid / TPR, aseg = tid % TPR;
    const float* aP = A + (size_t)(m0 + ar) * lda + aseg * FPT;

    const short* bg[nBI];
    {
        const int cs = (l & 7) ^ (l >> 3);
        const int plane = cs >> 2, kslot = cs & 3;
        #pragma unroll
        for (int j = 0; j < nBI; ++j) {
            const int col = (wid * nBI + j) * 8 + (l >> 3);
            bg[j] = Bsp + (size_t)plane * NK + (size_t)(n0 + col) * ldb + kslot * 8;
        }
    }

    f16v acc[MF][NFw];
    #pragma unroll
    for (int m = 0; m < MF; ++m)
        #pragma unroll
        for (int n = 0; n < NFw; ++n) acc[m][n] = (f16v)0.0f;

    f4v areg[FPT / 4];

    auto loadA = [&](int t) {
        const float* p = aP + t * 32;
        #pragma unroll
        for (int i = 0; i < FPT / 4; ++i) areg[i] = *(const f4v*)(p + i * 4);
    };
    auto stageB = [&](int t, short* buf) {
        short* Bb = buf + BM * 64;
        #pragma unroll
        for (int j = 0; j < nBI; ++j)
            gload_lds16(bg[j] + t * 32, Bb + (wid * nBI + j) * 512);
    };
    auto writeA = [&](short* buf) {
        #pragma unroll
        for (int c = 0; c < FPT / 8; ++c) {
            s8v hi, lo;
            #pragma unroll
            for (int e = 0; e < 8; ++e) {
                const float v = areg[c * 2 + (e >> 2)][e & 3];
                const short hs = f2bf(v);
                hi[e] = hs; lo[e] = f2bf(v - bf2f(hs));
            }
            const int csh = aseg * (FPT / 8) + c;
            *(s8v*)&buf[ar * 64 + ((csh    ) ^ (ar & 7)) * 8] = hi;
            *(s8v*)&buf[ar * 64 + ((csh + 4) ^ (ar & 7)) * 8] = lo;
        }
    };
    auto compute = [&](const short* buf) {
        const short* Ab = buf;
        const short* Bb = buf + BM * 64;
        #pragma unroll
        for (int ks = 0; ks < 2; ++ks) {
            const int csb = ks * 2 + (l >> 5);
            s8v ah[MF], al[MF], bh[NFw], bl[NFw];
            #pragma unroll
            for (int m = 0; m < MF; ++m) {
                const int row = wr * (BM / 2) + m * 32 + (l & 31);
                ah[m] = *(const s8v*)&Ab[row * 64 + ((csb    ) ^ (row & 7)) * 8];
                al[m] = *(const s8v*)&Ab[row * 64 + ((csb + 4) ^ (row & 7)) * 8];
            }
            #pragma unroll
            for (int n = 0; n < NFw; ++n) {
                const int col = wc * (BN / 2) + n * 32 + (l & 31);
                bh[n] = *(const s8v*)&Bb[col * 64 + ((csb    ) ^ (col & 7)) * 8];
                bl[n] = *(const s8v*)&Bb[col * 64 + ((csb + 4) ^ (col & 7)) * 8];
            }
            __builtin_amdgcn_s_setprio(1);
            #pragma unroll
            for (int m = 0; m < MF; ++m)
                #pragma unroll
                for (int n = 0; n < NFw; ++n) {
                    acc[m][n] = __builtin_amdgcn_mfma_f32_32x32x16_bf16(ah[m], bh[n], acc[m][n], 0, 0, 0);
                    acc[m][n] = __builtin_amdgcn_mfma_f32_32x32x16_bf16(ah[m], bl[n], acc[m][n], 0, 0, 0);
                    acc[m][n] = __builtin_amdgcn_mfma_f32_32x32x16_bf16(al[m], bh[n], acc[m][n], 0, 0, 0);
                }
            __builtin_amdgcn_s_setprio(0);
        }
    };

    const int NT = K / 32;
    loadA(0);
    stageB(0, smem);
    writeA(smem);
    __syncthreads();
    for (int t = 0; t < NT; ++t) {
        short* curb = smem + (t & 1) * BUF;
        short* nxtb = smem + ((t & 1) ^ 1) * BUF;
        const bool pf = (t + 1 < NT);
        if (pf) { loadA(t + 1); stageB(t + 1, nxtb); }
        compute(curb);
        if (pf) writeA(nxtb);
        __syncthreads();
    }

    if constexpr (EPI <= 1) {
        #pragma unroll
        for (int m = 0; m < MF; ++m) {
            #pragma unroll
            for (int n = 0; n < NFw; ++n) {
                const int gcol = n0 + wc * (BN / 2) + n * 32 + (l & 31);
                const float bv = bias[gcol];
                #pragma unroll
                for (int r = 0; r < 16; ++r) {
                    const int grow = m0 + wr * (BM / 2) + m * 32
                                   + (r & 3) + 8 * (r >> 2) + 4 * (l >> 5);
                    float xv = acc[m][n][r] + bv;
                    if constexpr (EPI == 0) xv = gelu_f(xv);
                    out[(size_t)grow * ostr + gcol] = xv;
                }
            }
        }
    } else {
        float* LT = reinterpret_cast<float*>(smem);   // [64][64]
        const int gcolL = wc * 32 + (l & 31);
        const float bv = bias[gcolL];
        #pragma unroll
        for (int r = 0; r < 16; ++r) {
            const int row = wr * 32 + (r & 3) + 8 * (r >> 2) + 4 * (l >> 5);
            LT[row * 64 + gcolL] = acc[0][0][r] + bv;
        }
        __syncthreads();
        const int r = tid >> 2, q = tid & 3;
        const float* Lr = LT + r * 64 + q * 16;
        float mx = Lr[0];
        #pragma unroll
        for (int c = 1; c < 16; ++c) mx = fmaxf(mx, Lr[c]);
        mx = fmaxf(mx, __shfl_xor(mx, 1));
        mx = fmaxf(mx, __shfl_xor(mx, 2));
        float ev[16]; float s = 0.0f;
        #pragma unroll
        for (int c = 0; c < 16; ++c) { ev[c] = expf(Lr[c] - mx); s += ev[c]; }
        s += __shfl_xor(s, 1);
        s += __shfl_xor(s, 2);
        float pmax = -1.0f; int arg = 0;
        #pragma unroll
        for (int c = 0; c < 16; ++c) {
            const float pv = ev[c] / s;
            out[(size_t)(m0 + r) * 64 + q * 16 + c] = pv;
            if (pv > pmax) { pmax = pv; arg = q * 16 + c; }
        }
        #pragma unroll
        for (int off = 1; off <= 2; off <<= 1) {
            const float po = __shfl_xor(pmax, off);
            const int   ao = __shfl_xor(arg, off);
            if (po > pmax || (po == pmax && ao < arg)) { pmax = po; arg = ao; }
        }
        if (q == 0) out2[m0 + r] = (float)arg;
    }
}

// ---------------------------------------------------------------------------
// LayerNorm(256) in place (round-3).
// ---------------------------------------------------------------------------
__global__ __launch_bounds__(256) void ln_kernel(float* __restrict__ H,
                                                 const float* __restrict__ G,
                                                 const float* __restrict__ Bv)
{
    const int row = blockIdx.x * 4 + (threadIdx.x >> 6);
    const int l   = threadIdx.x & 63;
    float* hr = H + (size_t)row * 256;
    f4v v = *reinterpret_cast<const f4v*>(&hr[l * 4]);
    float s = v[0] + v[1] + v[2] + v[3];
    #pragma unroll
    for (int o = 32; o; o >>= 1) s += __shfl_xor(s, o);
    const float mu = s * 0.00390625f;
    f4v d = v - mu;
    float q = d[0]*d[0] + d[1]*d[1] + d[2]*d[2] + d[3]*d[3];
    #pragma unroll
    for (int o = 32; o; o >>= 1) q += __shfl_xor(q, o);
    const float var = q * 0.00390625f;
    const float sc  = 1.0f / sqrtf(var + 1e-5f);
    f4v gg = *reinterpret_cast<const f4v*>(&G[l * 4]);
    f4v bb = *reinterpret_cast<const f4v*>(&Bv[l * 4]);
    f4v o4 = d * sc * gg + bb;
    *reinterpret_cast<f4v*>(&hr[l * 4]) = o4;
}

// ---------------------------------------------------------------------------
// Level head (round-3 math) as device fn; p_all runs all 3 per wave.
// ---------------------------------------------------------------------------
__device__ void p_head(int row, int l,
                       const float* __restrict__ X, int din,
                       const float* __restrict__ F, int fstr,
                       const float* __restrict__ W3d, const float* __restrict__ b3d,
                       const float* __restrict__ cc,
                       const float* __restrict__ rW, const float* __restrict__ rb,
                       float* __restrict__ dst)
{
    float px0 = 0.f, px1 = 0.f, px2 = 0.f;
    const int per = din >> 6;
    const float* xr = X + (size_t)row * din;
    for (int i = 0; i < per; ++i) {
        const int k = l + (i << 6);
        const float xv = xr[k];
        px0 += xv * W3d[k*3 + 0];
        px1 += xv * W3d[k*3 + 1];
        px2 += xv * W3d[k*3 + 2];
    }
    float g0 = 0.f, g1 = 0.f, g2 = 0.f, g3 = 0.f;
    const float* fr = F + (size_t)row * fstr;
    #pragma unroll
    for (int i = 0; i < 2; ++i) {
        const int k = l + (i << 6);
        const float fv = fr[k];
        g0 += fv * rW[k*4 + 0]; g1 += fv * rW[k*4 + 1];
        g2 += fv * rW[k*4 + 2]; g3 += fv * rW[k*4 + 3];
    }
    #pragma unroll
    for (int o = 32; o; o >>= 1) {
        px0 += __shfl_xor(px0, o); px1 += __shfl_xor(px1, o); px2 += __shfl_xor(px2, o);
        g0  += __shfl_xor(g0, o);  g1  += __shfl_xor(g1, o);
        g2  += __shfl_xor(g2, o);  g3  += __shfl_xor(g3, o);
    }
    if (l == 0) {
        const float pos0 = px0 + b3d[0], pos1 = px1 + b3d[1], pos2 = px2 + b3d[2];
        float lg[4];
        float mx = -1e30f;
        float gg[4] = {g0, g1, g2, g3};
        #pragma unroll
        for (int c = 0; c < 4; ++c) {
            float a = gg[c] + rb[c]
                    + pos0 * rW[512 + c] + pos1 * rW[516 + c] + pos2 * rW[520 + c];
            const float d0 = pos0 - cc[c*3 + 0];
            const float d1 = pos1 - cc[c*3 + 1];
            const float d2 = pos2 - cc[c*3 + 2];
            a += 0.5f * (-(d0*d0 + d1*d1 + d2*d2) / 2.00000001f);
            lg[c] = a;
            mx = fmaxf(mx, a);
        }
        const float e0 = expf(lg[0]-mx), e1 = expf(lg[1]-mx),
                    e2 = expf(lg[2]-mx), e3 = expf(lg[3]-mx);
        const float s = e0 + e1 + e2 + e3;
        dst[0] = e0/s; dst[1] = e1/s; dst[2] = e2/s; dst[3] = e3/s;
    }
}

struct PAllArgs {
    const float* h2; const float* f1; const float* f2; float* comb;
    const float* W3d[3]; const float* b3d[3]; const float* cc[3];
    const float* rW[3];  const float* rb[3];
};

__global__ __launch_bounds__(256) void p_all(PAllArgs A)
{
    const int row = blockIdx.x * 4 + (threadIdx.x >> 6);
    const int l   = threadIdx.x & 63;
    float* cr = A.comb + (size_t)row * 160;
    p_head(row, l, A.h2, 256, A.f1,  128, A.W3d[0], A.b3d[0], A.cc[0], A.rW[0], A.rb[0], cr + 128);
    p_head(row, l, A.f1, 128, A.f2,  128, A.W3d[1], A.b3d[1], A.cc[1], A.rW[1], A.rb[1], cr + 132);
    p_head(row, l, A.f2, 128, A.comb, 160, A.W3d[2], A.b3d[2], A.cc[2], A.rW[2], A.rb[2], cr + 136);
}

// ---------------------------------------------------------------------------
extern "C" void kernel_launch(void* const* d_in, const int* in_sizes, int n_in,
                              void* d_out, int out_size, void* d_ws, size_t ws_size,
                              hipStream_t stream)
{
    (void)in_sizes; (void)n_in; (void)out_size; (void)ws_size;

    const float* x    = (const float*)d_in[0];
    const float* ipW1 = (const float*)d_in[1];
    const float* ipb1 = (const float*)d_in[2];
    const float* ipW2 = (const float*)d_in[3];
    const float* ipb2 = (const float*)d_in[4];
    const float* ln_g = (const float*)d_in[5];
    const float* ln_b = (const float*)d_in[6];
    const float* W3d[3] = {(const float*)d_in[7],  (const float*)d_in[17], (const float*)d_in[27]};
    const float* b3d[3] = {(const float*)d_in[8],  (const float*)d_in[18], (const float*)d_in[28]};
    const float* cc[3]  = {(const float*)d_in[9],  (const float*)d_in[19], (const float*)d_in[29]};
    const float* f1W[3] = {(const float*)d_in[11], (const float*)d_in[21], (const float*)d_in[31]};
    const float* f1b[3] = {(const float*)d_in[12], (const float*)d_in[22], (const float*)d_in[32]};
    const float* f2W[3] = {(const float*)d_in[13], (const float*)d_in[23], (const float*)d_in[33]};
    const float* f2b[3] = {(const float*)d_in[14], (const float*)d_in[24], (const float*)d_in[34]};
    const float* rW[3]  = {(const float*)d_in[15], (const float*)d_in[25], (const float*)d_in[35]};
    const float* rb[3]  = {(const float*)d_in[16], (const float*)d_in[26], (const float*)d_in[36]};
    const float* ehW1 = (const float*)d_in[37];
    const float* ehb1 = (const float*)d_in[38];
    const float* ehW2 = (const float*)d_in[39];
    const float* ehb2 = (const float*)d_in[40];

    size_t off = 0;
    auto take = [&](size_t bytes) -> void* {
        void* p = (char*)d_ws + off;
        off += (bytes + 255) & ~(size_t)255;
        return p;
    };
    auto takeW = [&](int N, int Kpad) -> short* {
        return (short*)take((size_t)2 * N * Kpad * 2);
    };
    short* W1img = (short*)take((size_t)64 * 512 * 64 * 2);   // 4 MiB
    short* W2s = takeW(256, 512);
    short* L1a = takeW(128, 256);
    short* L1b = takeW(128, 128);
    short* L2a = takeW(128, 128);
    short* L2b = takeW(128, 128);
    short* L3a = takeW(128, 128);
    short* L3b = takeW(128, 128);
    short* E1s = takeW(256, 160);
    short* E2s = takeW(64, 256);
    float* h1  = (float*)take((size_t)B_ROWS * 512 * 4);
    float* h2  = (float*)take((size_t)B_ROWS * 256 * 4);
    float* zg  = (float*)take((size_t)B_ROWS * 128 * 4);
    float* f1  = (float*)take((size_t)B_ROWS * 128 * 4);
    float* f2  = (float*)take((size_t)B_ROWS * 128 * 4);
    float* geh = (float*)take((size_t)B_ROWS * 256 * 4);
    float* comb = h1;                              // [B][160], h1 dead after gemm2

    // ---- weight pre-passes ----
    split_w1_img<<<(64 * 512 * 8) / 256, 256, 0, stream>>>(ipW1, W1img);
    SplitPack sp;
    int blk = 0;
    auto desc = [&](int i, const float* W, short* dst, int K, int N, int Kpad) {
        sp.d[i] = {W, dst, K, N, Kpad, blk};
        blk += (N * Kpad + 255) / 256;
    };
    desc(0, ipW2,   W2s,  512, 256,  512);
    desc(1, f1W[0], L1a,  256, 128,  256);
    desc(2, f2W[0], L1b,  128, 128,  128);
    desc(3, f1W[1], L2a,  128, 128,  128);
    desc(4, f2W[1], L2b,  128, 128,  128);
    desc(5, f1W[2], L3a,  128, 128,  128);
    desc(6, f2W[2], L3b,  128, 128,  128);
    desc(7, ehW1,   E1s,  140, 256,  160);
    desc(8, ehW2,   E2s,  256,  64,  256);
    split_all<<<blk, 256, 0, stream>>>(sp);

    const dim3 blkT(256);
    constexpr int MG64 = B_ROWS / 64;   // 512

    // input_proj (gemm2 at BM=64: 1024 blocks, 4/CU)
    gemm1k<<<1024, blkT, 0, stream>>>(x, W1img, ipb1, h1);
    gemm32<64,128,1><<<MG64*2, blkT, 0, stream>>>(h1, 512, W2s, 512, 256*512, ipb2,
                                                  512, 256, 2, 256, h2, nullptr);
    ln_kernel<<<B_ROWS/4, 256, 0, stream>>>(h2, ln_g, ln_b);

    // levels at BN=64/ntiles=2: 1024 blocks each, 4-5 blocks/CU
    gemm32<64,64,0><<<MG64*2, blkT, 0, stream>>>(h2, 256, L1a, 256, 128*256, f1b[0], 256, 128, 2, 128, zg, nullptr);
    gemm32<64,64,1><<<MG64*2, blkT, 0, stream>>>(zg, 128, L1b, 128, 128*128, f2b[0], 128, 128, 2, 128, f1, nullptr);
    gemm32<64,64,0><<<MG64*2, blkT, 0, stream>>>(f1, 128, L2a, 128, 128*128, f1b[1], 128, 128, 2, 128, zg, nullptr);
    gemm32<64,64,1><<<MG64*2, blkT, 0, stream>>>(zg, 128, L2b, 128, 128*128, f2b[1], 128, 128, 2, 128, f2, nullptr);
    gemm32<64,64,0><<<MG64*2, blkT, 0, stream>>>(f2, 128, L3a, 128, 128*128, f1b[2], 128, 128, 2, 128, zg, nullptr);
    gemm32<64,64,1><<<MG64*2, blkT, 0, stream>>>(zg, 128, L3b, 128, 128*128, f2b[2], 128, 128, 2, 160, comb, nullptr);

    // all three p-heads in one launch (inputs h2,f1,f2,comb all ready)
    PAllArgs pa;
    pa.h2 = h2; pa.f1 = f1; pa.f2 = f2; pa.comb = comb;
    for (int i = 0; i < 3; ++i) {
        pa.W3d[i] = W3d[i]; pa.b3d[i] = b3d[i]; pa.cc[i] = cc[i];
        pa.rW[i] = rW[i];   pa.rb[i] = rb[i];
    }
    p_all<<<B_ROWS/4, 256, 0, stream>>>(pa);

    // expert head (comb cols 140-159 stale but hit zero E1 pad rows)
    gemm32<64,128,0><<<MG64*2, blkT, 0, stream>>>(comb, 160, E1s, 160, 256*160, ehb1,
                                                  160, 256, 2, 256, geh, nullptr);
    gemm32<64,64,2><<<MG64, blkT, 0, stream>>>(geh, 256, E2s, 256, 64*256, ehb2,
                                               256, 64, 1, 64, (float*)d_out,
                                               (float*)d_out + (size_t)B_ROWS * 64);
}

// Round 11
// 461.639 us; speedup vs baseline: 1.0355x; 1.0355x over previous
//
#include <hip/hip_runtime.h>
#include <hip/hip_bf16.h>
#include <cstdint>
#include <cstddef>

// ---------------------------------------------------------------------------
// EnhancedBVHRouter forward, MI355X/gfx950. Round 11 = round-7 exact restore
// (best measured configuration of the session: 462us).
//  - gemm1k: 128x128 tile, BK=32, 4 blk/CU, A-panel-sharing XCD swizzle,
//    B via pre-swizzled LDS-image + global_load_lds, fused A hi/lo cvt.
//  - tail: gemm32 pairs (ostr variant), p_all single launch, concat
//    eliminated (strided writes into comb), EH2 fused softmax+argmax.
// All GEMMs bf16x3 (hi/lo split, 3 MFMA), f32-class precision.
// ---------------------------------------------------------------------------

typedef short  s8v  __attribute__((ext_vector_type(8)));
typedef float  f4v  __attribute__((ext_vector_type(4)));
typedef float  f16v __attribute__((ext_vector_type(16)));
typedef unsigned int u32;

#define B_ROWS 32768

__device__ inline short f2bf(float x) {
    __hip_bfloat16 h = __float2bfloat16(x);
    return __builtin_bit_cast(short, h);
}
__device__ inline float bf2f(short s) {
    return __bfloat162float(__builtin_bit_cast(__hip_bfloat16, s));
}
__device__ inline float gelu_f(float x) {
    return 0.5f * x * (1.0f + erff(x * 0.70710678118654752440f));
}
__device__ inline void gload_lds16(const short* g, short* l) {
    __builtin_amdgcn_global_load_lds(
        (const __attribute__((address_space(1))) u32*)g,
        (__attribute__((address_space(3))) u32*)l, 16, 0, 0);
}

// ---------------------------------------------------------------------------
// W1 -> LDS-image (round-3 proven).
// ---------------------------------------------------------------------------
__global__ void split_w1_img(const float* __restrict__ W, short* __restrict__ img)
{
    const int idx = blockIdx.x * 256 + threadIdx.x;     // 64*512*8 total
    const int p = idx & 7;
    const int n = (idx >> 3) & 511;
    const int t = idx >> 12;
    const int cs = p ^ (n & 7);
    const int plane = cs >> 2, kc = cs & 3;
    const int kbase = t * 32 + kc * 8;
    s8v v8;
    #pragma unroll
    for (int e = 0; e < 8; ++e) {
        const float v = W[(size_t)(kbase + e) * 512 + n];
        const short h = f2bf(v);
        v8[e] = plane ? f2bf(v - bf2f(h)) : h;
    }
    *(s8v*)&img[(size_t)((t * 512 + n) * 64 + p * 8)] = v8;
}

// ---------------------------------------------------------------------------
// GEMM1 (round-7 exact: proven 285us).
// ---------------------------------------------------------------------------
__launch_bounds__(256, 4)
__global__ void gemm1k(const float* __restrict__ X,
                       const short* __restrict__ Bimg,
                       const float* __restrict__ bias,
                       float* __restrict__ out)
{
    __shared__ short smem[128 * 64 * 2];
    short* Ab = smem;
    short* Bb = smem + 128 * 64;

    const int tid = threadIdx.x;
    const int l = tid & 63, wid = tid >> 6;
    const int wr = wid >> 1, wc = wid & 1;

    // A-panel-sharing swizzle (round-7 proven: FETCH 538->192MB)
    const int d = blockIdx.x;                 // 1024 blocks
    const int xcd = d & 7, s = d >> 3;
    const int m0 = (xcd * 32 + (s >> 2)) * 128;
    const int n0 = (s & 3) * 128;

    const int ar = tid & 127, ah = tid >> 7;
    const float* xP = X + (size_t)(m0 + ar) * 2048 + ah * 16;
    short* awr = Ab + ar * 64;
    const int pw0 = ((ah * 2    ) ^ (ar & 7)) * 8;
    const int pw1 = ((ah * 2 + 1) ^ (ar & 7)) * 8;
    const int pw2 = ((ah * 2 + 4) ^ (ar & 7)) * 8;
    const int pw3 = ((ah * 2 + 5) ^ (ar & 7)) * 8;

    const short* bP = Bimg + (size_t)n0 * 64 + (size_t)(wid * 4) * 512 + (size_t)l * 8;
    short* bD = Bb + wid * 4 * 512;

    f16v acc[2][2];
    #pragma unroll
    for (int m = 0; m < 2; ++m)
        #pragma unroll
        for (int n = 0; n < 2; ++n) acc[m][n] = (f16v)0.0f;

    f4v cur0, cur1, cur2, cur3;
    cur0 = *(const f4v*)(xP + 0);
    cur1 = *(const f4v*)(xP + 4);
    cur2 = *(const f4v*)(xP + 8);
    cur3 = *(const f4v*)(xP + 12);

    for (int t = 0; t < 64; ++t) {
        s8v hi0, hi1, lo0, lo1;
        #pragma unroll
        for (int e = 0; e < 4; ++e) {
            float v;
            short h;
            v = cur0[e]; h = f2bf(v); hi0[e]     = h; lo0[e]     = f2bf(v - bf2f(h));
            v = cur1[e]; h = f2bf(v); hi0[e + 4] = h; lo0[e + 4] = f2bf(v - bf2f(h));
            v = cur2[e]; h = f2bf(v); hi1[e]     = h; lo1[e]     = f2bf(v - bf2f(h));
            v = cur3[e]; h = f2bf(v); hi1[e + 4] = h; lo1[e + 4] = f2bf(v - bf2f(h));
        }
        __syncthreads();
        *(s8v*)&awr[pw0] = hi0;
        *(s8v*)&awr[pw1] = hi1;
        *(s8v*)&awr[pw2] = lo0;
        *(s8v*)&awr[pw3] = lo1;
        {
            const short* bt = bP + (size_t)t * 32768;
            gload_lds16(bt,          bD);
            gload_lds16(bt +  512,   bD + 512);
            gload_lds16(bt + 1024,   bD + 1024);
            gload_lds16(bt + 1536,   bD + 1536);
        }
        if (t < 63) {
            const float* p = xP + (t + 1) * 32;
            cur0 = *(const f4v*)(p + 0);
            cur1 = *(const f4v*)(p + 4);
            cur2 = *(const f4v*)(p + 8);
            cur3 = *(const f4v*)(p + 12);
        }
        __syncthreads();

        #pragma unroll
        for (int ks = 0; ks < 2; ++ks) {
            const int ph0 = ks * 2 + (l >> 5);
            s8v ahf[2], alf[2], bhf[2], blf[2];
            #pragma unroll
            for (int m = 0; m < 2; ++m) {
                const int row = wr * 64 + m * 32 + (l & 31);
                const int ph = ph0 ^ (row & 7);
                ahf[m] = *(const s8v*)&Ab[row * 64 + ph * 8];
                alf[m] = *(const s8v*)&Ab[row * 64 + (ph ^ 4) * 8];
            }
            #pragma unroll
            for (int n = 0; n < 2; ++n) {
                const int col = wc * 64 + n * 32 + (l & 31);
                const int ph = ph0 ^ (col & 7);
                bhf[n] = *(const s8v*)&Bb[col * 64 + ph * 8];
                blf[n] = *(const s8v*)&Bb[col * 64 + (ph ^ 4) * 8];
            }
            #pragma unroll
            for (int m = 0; m < 2; ++m)
                #pragma unroll
                for (int n = 0; n < 2; ++n) {
                    acc[m][n] = __builtin_amdgcn_mfma_f32_32x32x16_bf16(ahf[m], bhf[n], acc[m][n], 0, 0, 0);
                    acc[m][n] = __builtin_amdgcn_mfma_f32_32x32x16_bf16(ahf[m], blf[n], acc[m][n], 0, 0, 0);
                    acc[m][n] = __builtin_amdgcn_mfma_f32_32x32x16_bf16(alf[m], bhf[n], acc[m][n], 0, 0, 0);
                }
        }
    }

    #pragma unroll
    for (int m = 0; m < 2; ++m) {
        #pragma unroll
        for (int n = 0; n < 2; ++n) {
            const int gcol = n0 + wc * 64 + n * 32 + (l & 31);
            const float bv = bias[gcol];
            #pragma unroll
            for (int r = 0; r < 16; ++r) {
                const int grow = m0 + wr * 64 + m * 32
                               + (r & 3) + 8 * (r >> 2) + 4 * (l >> 5);
                out[(size_t)grow * 512 + gcol] = gelu_f(acc[m][n][r] + bv);
            }
        }
    }
}

// ---------------------------------------------------------------------------
// Weight split: W (K x N f32) -> [2][N][Kpad] bf16 planes.
// ---------------------------------------------------------------------------
struct SplitDesc { const float* W; short* dst; int K, N, Kpad, blk0; };
struct SplitPack { SplitDesc d[9]; };

__global__ void split_all(SplitPack p) {
    const int bid = blockIdx.x;
    int i = 0;
    #pragma unroll
    for (int j = 1; j < 9; ++j) if (bid >= p.d[j].blk0) i = j;
    const SplitDesc& D = p.d[i];
    const int idx = (bid - D.blk0) * 256 + threadIdx.x;
    const int total = D.N * D.Kpad;
    if (idx >= total) return;
    const int n = idx / D.Kpad, k = idx - n * D.Kpad;
    const float v = (k < D.K) ? D.W[(size_t)k * D.N + n] : 0.0f;
    const short hs = f2bf(v);
    D.dst[idx] = hs;
    D.dst[total + idx] = f2bf(v - bf2f(hs));
}

// ---------------------------------------------------------------------------
// gemm32 (round-7): bf16x3, dbuf LDS, 2-phase prefetch, output stride.
// EPI: 0 = +bias,gelu ; 1 = +bias ; 2 = softmax64+argmax (ostr unused).
// ---------------------------------------------------------------------------
template<int BM, int BN, int EPI>
__launch_bounds__(256, 2)
__global__ void gemm32(const float* __restrict__ A, int lda,
                       const short* __restrict__ Bsp, int ldb, int NK,
                       const float* __restrict__ bias, int K, int N, int ntiles,
                       int ostr, float* __restrict__ out, float* __restrict__ out2)
{
    constexpr int MF  = BM / 64;
    constexpr int NFw = BN / 64;
    constexpr int BUF = (BM + BN) * 64;
    constexpr int FPT = BM / 8;
    constexpr int TPR = 32 / FPT;
    constexpr int nBI = BN / 32;
    __shared__ short smem[2 * BUF];

    const int tid = threadIdx.x;
    const int l   = tid & 63, wid = tid >> 6;
    const int wr  = wid >> 1, wc = wid & 1;
    const int bid = blockIdx.x;
    const int ntb = bid % ntiles, mtb = bid / ntiles;
    const int m0  = mtb * BM, n0 = ntb * BN;

    const int ar = tid / TPR, aseg = tid % TPR;
    const float* aP = A + (size_t)(m0 + ar) * lda + aseg * FPT;

    const short* bg[nBI];
    {
        const int cs = (l & 7) ^ (l >> 3);
        const int plane = cs >> 2, kslot = cs & 3;
        #pragma unroll
        for (int j = 0; j < nBI; ++j) {
            const int col = (wid * nBI + j) * 8 + (l >> 3);
            bg[j] = Bsp + (size_t)plane * NK + (size_t)(n0 + col) * ldb + kslot * 8;
        }
    }

    f16v acc[MF][NFw];
    #pragma unroll
    for (int m = 0; m < MF; ++m)
        #pragma unroll
        for (int n = 0; n < NFw; ++n) acc[m][n] = (f16v)0.0f;

    f4v areg[FPT / 4];

    auto loadA = [&](int t) {
        const float* p = aP + t * 32;
        #pragma unroll
        for (int i = 0; i < FPT / 4; ++i) areg[i] = *(const f4v*)(p + i * 4);
    };
    auto stageB = [&](int t, short* buf) {
        short* Bb = buf + BM * 64;
        #pragma unroll
        for (int j = 0; j < nBI; ++j)
            gload_lds16(bg[j] + t * 32, Bb + (wid * nBI + j) * 512);
    };
    auto writeA = [&](short* buf) {
        #pragma unroll
        for (int c = 0; c < FPT / 8; ++c) {
            s8v hi, lo;
            #pragma unroll
            for (int e = 0; e < 8; ++e) {
                const float v = areg[c * 2 + (e >> 2)][e & 3];
                const short hs = f2bf(v);
                hi[e] = hs; lo[e] = f2bf(v - bf2f(hs));
            }
            const int csh = aseg * (FPT / 8) + c;
            *(s8v*)&buf[ar * 64 + ((csh    ) ^ (ar & 7)) * 8] = hi;
            *(s8v*)&buf[ar * 64 + ((csh + 4) ^ (ar & 7)) * 8] = lo;
        }
    };
    auto compute = [&](const short* buf) {
        const short* Ab = buf;
        const short* Bb = buf + BM * 64;
        #pragma unroll
        for (int ks = 0; ks < 2; ++ks) {
            const int csb = ks * 2 + (l >> 5);
            s8v ah[MF], al[MF], bh[NFw], bl[NFw];
            #pragma unroll
            for (int m = 0; m < MF; ++m) {
                const int row = wr * (BM / 2) + m * 32 + (l & 31);
                ah[m] = *(const s8v*)&Ab[row * 64 + ((csb    ) ^ (row & 7)) * 8];
                al[m] = *(const s8v*)&Ab[row * 64 + ((csb + 4) ^ (row & 7)) * 8];
            }
            #pragma unroll
            for (int n = 0; n < NFw; ++n) {
                const int col = wc * (BN / 2) + n * 32 + (l & 31);
                bh[n] = *(const s8v*)&Bb[col * 64 + ((csb    ) ^ (col & 7)) * 8];
                bl[n] = *(const s8v*)&Bb[col * 64 + ((csb + 4) ^ (col & 7)) * 8];
            }
            __builtin_amdgcn_s_setprio(1);
            #pragma unroll
            for (int m = 0; m < MF; ++m)
                #pragma unroll
                for (int n = 0; n < NFw; ++n) {
                    acc[m][n] = __builtin_amdgcn_mfma_f32_32x32x16_bf16(ah[m], bh[n], acc[m][n], 0, 0, 0);
                    acc[m][n] = __builtin_amdgcn_mfma_f32_32x32x16_bf16(ah[m], bl[n], acc[m][n], 0, 0, 0);
                    acc[m][n] = __builtin_amdgcn_mfma_f32_32x32x16_bf16(al[m], bh[n], acc[m][n], 0, 0, 0);
                }
            __builtin_amdgcn_s_setprio(0);
        }
    };

    const int NT = K / 32;
    loadA(0);
    stageB(0, smem);
    writeA(smem);
    __syncthreads();
    for (int t = 0; t < NT; ++t) {
        short* curb = smem + (t & 1) * BUF;
        short* nxtb = smem + ((t & 1) ^ 1) * BUF;
        const bool pf = (t + 1 < NT);
        if (pf) { loadA(t + 1); stageB(t + 1, nxtb); }
        compute(curb);
        if (pf) writeA(nxtb);
        __syncthreads();
    }

    if constexpr (EPI <= 1) {
        #pragma unroll
        for (int m = 0; m < MF; ++m) {
            #pragma unroll
            for (int n = 0; n < NFw; ++n) {
                const int gcol = n0 + wc * (BN / 2) + n * 32 + (l & 31);
                const float bv = bias[gcol];
                #pragma unroll
                for (int r = 0; r < 16; ++r) {
                    const int grow = m0 + wr * (BM / 2) + m * 32
                                   + (r & 3) + 8 * (r >> 2) + 4 * (l >> 5);
                    float xv = acc[m][n][r] + bv;
                    if constexpr (EPI == 0) xv = gelu_f(xv);
                    out[(size_t)grow * ostr + gcol] = xv;
                }
            }
        }
    } else {
        float* LT = reinterpret_cast<float*>(smem);   // [64][64]
        const int gcolL = wc * 32 + (l & 31);
        const float bv = bias[gcolL];
        #pragma unroll
        for (int r = 0; r < 16; ++r) {
            const int row = wr * 32 + (r & 3) + 8 * (r >> 2) + 4 * (l >> 5);
            LT[row * 64 + gcolL] = acc[0][0][r] + bv;
        }
        __syncthreads();
        const int r = tid >> 2, q = tid & 3;
        const float* Lr = LT + r * 64 + q * 16;
        float mx = Lr[0];
        #pragma unroll
        for (int c = 1; c < 16; ++c) mx = fmaxf(mx, Lr[c]);
        mx = fmaxf(mx, __shfl_xor(mx, 1));
        mx = fmaxf(mx, __shfl_xor(mx, 2));
        float ev[16]; float s = 0.0f;
        #pragma unroll
        for (int c = 0; c < 16; ++c) { ev[c] = expf(Lr[c] - mx); s += ev[c]; }
        s += __shfl_xor(s, 1);
        s += __shfl_xor(s, 2);
        float pmax = -1.0f; int arg = 0;
        #pragma unroll
        for (int c = 0; c < 16; ++c) {
            const float pv = ev[c] / s;
            out[(size_t)(m0 + r) * 64 + q * 16 + c] = pv;
            if (pv > pmax) { pmax = pv; arg = q * 16 + c; }
        }
        #pragma unroll
        for (int off = 1; off <= 2; off <<= 1) {
            const float po = __shfl_xor(pmax, off);
            const int   ao = __shfl_xor(arg, off);
            if (po > pmax || (po == pmax && ao < arg)) { pmax = po; arg = ao; }
        }
        if (q == 0) out2[m0 + r] = (float)arg;
    }
}

// ---------------------------------------------------------------------------
// LayerNorm(256) in place (round-3).
// ---------------------------------------------------------------------------
__global__ __launch_bounds__(256) void ln_kernel(float* __restrict__ H,
                                                 const float* __restrict__ G,
                                                 const float* __restrict__ Bv)
{
    const int row = blockIdx.x * 4 + (threadIdx.x >> 6);
    const int l   = threadIdx.x & 63;
    float* hr = H + (size_t)row * 256;
    f4v v = *reinterpret_cast<const f4v*>(&hr[l * 4]);
    float s = v[0] + v[1] + v[2] + v[3];
    #pragma unroll
    for (int o = 32; o; o >>= 1) s += __shfl_xor(s, o);
    const float mu = s * 0.00390625f;
    f4v d = v - mu;
    float q = d[0]*d[0] + d[1]*d[1] + d[2]*d[2] + d[3]*d[3];
    #pragma unroll
    for (int o = 32; o; o >>= 1) q += __shfl_xor(q, o);
    const float var = q * 0.00390625f;
    const float sc  = 1.0f / sqrtf(var + 1e-5f);
    f4v gg = *reinterpret_cast<const f4v*>(&G[l * 4]);
    f4v bb = *reinterpret_cast<const f4v*>(&Bv[l * 4]);
    f4v o4 = d * sc * gg + bb;
    *reinterpret_cast<f4v*>(&hr[l * 4]) = o4;
}

// ---------------------------------------------------------------------------
// Level head (round-3 math) as device fn; p_all runs all 3 per wave.
// ---------------------------------------------------------------------------
__device__ void p_head(int row, int l,
                       const float* __restrict__ X, int din,
                       const float* __restrict__ F, int fstr,
                       const float* __restrict__ W3d, const float* __restrict__ b3d,
                       const float* __restrict__ cc,
                       const float* __restrict__ rW, const float* __restrict__ rb,
                       float* __restrict__ dst)
{
    float px0 = 0.f, px1 = 0.f, px2 = 0.f;
    const int per = din >> 6;
    const float* xr = X + (size_t)row * din;
    for (int i = 0; i < per; ++i) {
        const int k = l + (i << 6);
        const float xv = xr[k];
        px0 += xv * W3d[k*3 + 0];
        px1 += xv * W3d[k*3 + 1];
        px2 += xv * W3d[k*3 + 2];
    }
    float g0 = 0.f, g1 = 0.f, g2 = 0.f, g3 = 0.f;
    const float* fr = F + (size_t)row * fstr;
    #pragma unroll
    for (int i = 0; i < 2; ++i) {
        const int k = l + (i << 6);
        const float fv = fr[k];
        g0 += fv * rW[k*4 + 0]; g1 += fv * rW[k*4 + 1];
        g2 += fv * rW[k*4 + 2]; g3 += fv * rW[k*4 + 3];
    }
    #pragma unroll
    for (int o = 32; o; o >>= 1) {
        px0 += __shfl_xor(px0, o); px1 += __shfl_xor(px1, o); px2 += __shfl_xor(px2, o);
        g0  += __shfl_xor(g0, o);  g1  += __shfl_xor(g1, o);
        g2  += __shfl_xor(g2, o);  g3  += __shfl_xor(g3, o);
    }
    if (l == 0) {
        const float pos0 = px0 + b3d[0], pos1 = px1 + b3d[1], pos2 = px2 + b3d[2];
        float lg[4];
        float mx = -1e30f;
        float gg[4] = {g0, g1, g2, g3};
        #pragma unroll
        for (int c = 0; c < 4; ++c) {
            float a = gg[c] + rb[c]
                    + pos0 * rW[512 + c] + pos1 * rW[516 + c] + pos2 * rW[520 + c];
            const float d0 = pos0 - cc[c*3 + 0];
            const float d1 = pos1 - cc[c*3 + 1];
            const float d2 = pos2 - cc[c*3 + 2];
            a += 0.5f * (-(d0*d0 + d1*d1 + d2*d2) / 2.00000001f);
            lg[c] = a;
            mx = fmaxf(mx, a);
        }
        const float e0 = expf(lg[0]-mx), e1 = expf(lg[1]-mx),
                    e2 = expf(lg[2]-mx), e3 = expf(lg[3]-mx);
        const float s = e0 + e1 + e2 + e3;
        dst[0] = e0/s; dst[1] = e1/s; dst[2] = e2/s; dst[3] = e3/s;
    }
}

struct PAllArgs {
    const float* h2; const float* f1; const float* f2; float* comb;
    const float* W3d[3]; const float* b3d[3]; const float* cc[3];
    const float* rW[3];  const float* rb[3];
};

__global__ __launch_bounds__(256) void p_all(PAllArgs A)
{
    const int row = blockIdx.x * 4 + (threadIdx.x >> 6);
    const int l   = threadIdx.x & 63;
    float* cr = A.comb + (size_t)row * 160;
    p_head(row, l, A.h2, 256, A.f1,  128, A.W3d[0], A.b3d[0], A.cc[0], A.rW[0], A.rb[0], cr + 128);
    p_head(row, l, A.f1, 128, A.f2,  128, A.W3d[1], A.b3d[1], A.cc[1], A.rW[1], A.rb[1], cr + 132);
    p_head(row, l, A.f2, 128, A.comb, 160, A.W3d[2], A.b3d[2], A.cc[2], A.rW[2], A.rb[2], cr + 136);
}

// ---------------------------------------------------------------------------
extern "C" void kernel_launch(void* const* d_in, const int* in_sizes, int n_in,
                              void* d_out, int out_size, void* d_ws, size_t ws_size,
                              hipStream_t stream)
{
    (void)in_sizes; (void)n_in; (void)out_size; (void)ws_size;

    const float* x    = (const float*)d_in[0];
    const float* ipW1 = (const float*)d_in[1];
    const float* ipb1 = (const float*)d_in[2];
    const float* ipW2 = (const float*)d_in[3];
    const float* ipb2 = (const float*)d_in[4];
    const float* ln_g = (const float*)d_in[5];
    const float* ln_b = (const float*)d_in[6];
    const float* W3d[3] = {(const float*)d_in[7],  (const float*)d_in[17], (const float*)d_in[27]};
    const float* b3d[3] = {(const float*)d_in[8],  (const float*)d_in[18], (const float*)d_in[28]};
    const float* cc[3]  = {(const float*)d_in[9],  (const float*)d_in[19], (const float*)d_in[29]};
    const float* f1W[3] = {(const float*)d_in[11], (const float*)d_in[21], (const float*)d_in[31]};
    const float* f1b[3] = {(const float*)d_in[12], (const float*)d_in[22], (const float*)d_in[32]};
    const float* f2W[3] = {(const float*)d_in[13], (const float*)d_in[23], (const float*)d_in[33]};
    const float* f2b[3] = {(const float*)d_in[14], (const float*)d_in[24], (const float*)d_in[34]};
    const float* rW[3]  = {(const float*)d_in[15], (const float*)d_in[25], (const float*)d_in[35]};
    const float* rb[3]  = {(const float*)d_in[16], (const float*)d_in[26], (const float*)d_in[36]};
    const float* ehW1 = (const float*)d_in[37];
    const float* ehb1 = (const float*)d_in[38];
    const float* ehW2 = (const float*)d_in[39];
    const float* ehb2 = (const float*)d_in[40];

    size_t off = 0;
    auto take = [&](size_t bytes) -> void* {
        void* p = (char*)d_ws + off;
        off += (bytes + 255) & ~(size_t)255;
        return p;
    };
    auto takeW = [&](int N, int Kpad) -> short* {
        return (short*)take((size_t)2 * N * Kpad * 2);
    };
    short* W1img = (short*)take((size_t)64 * 512 * 64 * 2);   // 4 MiB
    short* W2s = takeW(256, 512);
    short* L1a = takeW(128, 256);
    short* L1b = takeW(128, 128);
    short* L2a = takeW(128, 128);
    short* L2b = takeW(128, 128);
    short* L3a = takeW(128, 128);
    short* L3b = takeW(128, 128);
    short* E1s = takeW(256, 160);
    short* E2s = takeW(64, 256);
    float* h1  = (float*)take((size_t)B_ROWS * 512 * 4);
    float* h2  = (float*)take((size_t)B_ROWS * 256 * 4);
    float* zg  = (float*)take((size_t)B_ROWS * 128 * 4);
    float* f1  = (float*)take((size_t)B_ROWS * 128 * 4);
    float* f2  = (float*)take((size_t)B_ROWS * 128 * 4);
    float* geh = (float*)take((size_t)B_ROWS * 256 * 4);
    float* comb = h1;                              // [B][160], h1 dead after gemm2

    // ---- weight pre-passes ----
    split_w1_img<<<(64 * 512 * 8) / 256, 256, 0, stream>>>(ipW1, W1img);
    SplitPack sp;
    int blk = 0;
    auto desc = [&](int i, const float* W, short* dst, int K, int N, int Kpad) {
        sp.d[i] = {W, dst, K, N, Kpad, blk};
        blk += (N * Kpad + 255) / 256;
    };
    desc(0, ipW2,   W2s,  512, 256,  512);
    desc(1, f1W[0], L1a,  256, 128,  256);
    desc(2, f2W[0], L1b,  128, 128,  128);
    desc(3, f1W[1], L2a,  128, 128,  128);
    desc(4, f2W[1], L2b,  128, 128,  128);
    desc(5, f1W[2], L3a,  128, 128,  128);
    desc(6, f2W[2], L3b,  128, 128,  128);
    desc(7, ehW1,   E1s,  140, 256,  160);
    desc(8, ehW2,   E2s,  256,  64,  256);
    split_all<<<blk, 256, 0, stream>>>(sp);

    const dim3 blkT(256);
    constexpr int MG128 = B_ROWS / 128;  // 256
    constexpr int MG64  = B_ROWS / 64;   // 512

    // input_proj
    gemm1k<<<1024, blkT, 0, stream>>>(x, W1img, ipb1, h1);
    gemm32<128,128,1><<<MG128*2, blkT, 0, stream>>>(h1, 512, W2s, 512, 256*512, ipb2,
                                                    512, 256, 2, 256, h2, nullptr);
    ln_kernel<<<B_ROWS/4, 256, 0, stream>>>(h2, ln_g, ln_b);

    // levels (gemm pairs; L3b writes f3 straight into comb at stride 160)
    gemm32<64,128,0><<<MG64, blkT, 0, stream>>>(h2, 256, L1a, 256, 128*256, f1b[0], 256, 128, 1, 128, zg, nullptr);
    gemm32<64,128,1><<<MG64, blkT, 0, stream>>>(zg, 128, L1b, 128, 128*128, f2b[0], 128, 128, 1, 128, f1, nullptr);
    gemm32<64,128,0><<<MG64, blkT, 0, stream>>>(f1, 128, L2a, 128, 128*128, f1b[1], 128, 128, 1, 128, zg, nullptr);
    gemm32<64,128,1><<<MG64, blkT, 0, stream>>>(zg, 128, L2b, 128, 128*128, f2b[1], 128, 128, 1, 128, f2, nullptr);
    gemm32<64,128,0><<<MG64, blkT, 0, stream>>>(f2, 128, L3a, 128, 128*128, f1b[2], 128, 128, 1, 128, zg, nullptr);
    gemm32<64,128,1><<<MG64, blkT, 0, stream>>>(zg, 128, L3b, 128, 128*128, f2b[2], 128, 128, 1, 160, comb, nullptr);

    // all three p-heads in one launch (inputs h2,f1,f2,comb all ready)
    PAllArgs pa;
    pa.h2 = h2; pa.f1 = f1; pa.f2 = f2; pa.comb = comb;
    for (int i = 0; i < 3; ++i) {
        pa.W3d[i] = W3d[i]; pa.b3d[i] = b3d[i]; pa.cc[i] = cc[i];
        pa.rW[i] = rW[i];   pa.rb[i] = rb[i];
    }
    p_all<<<B_ROWS/4, 256, 0, stream>>>(pa);

    // expert head (comb cols 140-159 stale but hit zero E1 pad rows)
    gemm32<64,128,0><<<MG64*2, blkT, 0, stream>>>(comb, 160, E1s, 160, 256*160, ehb1,
                                                  160, 256, 2, 256, geh, nullptr);
    gemm32<64,64,2><<<MG64, blkT, 0, stream>>>(geh, 256, E2s, 256, 64*256, ehb2,
                                               256, 64, 1, 64, (float*)d_out,
                                               (float*)d_out + (size_t)B_ROWS * 64);
}